// Round 8
// baseline (523.259 us; speedup 1.0000x reference)
//
#include <hip/hip_runtime.h>

#define Sn 1024
#define Dn 64
#define PH_LD 1032   // ushorts/row: 516 dw ≡ 4 (mod 32) -> balanced b64 write / b128 read / b64 read
#define K_LD 72
#define V_LD 72

typedef short v8s __attribute__((ext_vector_type(8)));
typedef unsigned short v8u __attribute__((ext_vector_type(8)));
typedef float v4f __attribute__((ext_vector_type(4)));
typedef int   v4i __attribute__((ext_vector_type(4)));

__device__ __forceinline__ unsigned short f2bf(float x) {
    union { float f; unsigned u; } v; v.f = x;
    return (unsigned short)((v.u + 0x7FFFu + ((v.u >> 16) & 1u)) >> 16);
}
__device__ __forceinline__ float bf2f(unsigned short h) {
    union { float f; unsigned u; } v; v.u = ((unsigned)h) << 16;
    return v.f;
}
__device__ __forceinline__ void split2(float x, unsigned short& h, unsigned short& l) {
    unsigned short hs = f2bf(x);
    h = hs; l = f2bf(x - bf2f(hs));
}

// ---------------- prep: K -> Khi/Klo bf16 (flat) ----------------
__global__ __launch_bounds__(256) void prep_k(const float* __restrict__ K,
    unsigned short* __restrict__ Khi, unsigned short* __restrict__ Klo)
{
    const size_t i = (((size_t)blockIdx.x << 8) + threadIdx.x) << 3;
    const v4f x0 = __builtin_nontemporal_load((const v4f*)(K + i));
    const v4f x1 = __builtin_nontemporal_load((const v4f*)(K + i + 4));
    float x[8];
    *(v4f*)&x[0] = x0;
    *(v4f*)&x[4] = x1;
    v8u h, l;
    #pragma unroll
    for (int j = 0; j < 8; ++j) {
        unsigned short hh, ll;
        split2(x[j], hh, ll);
        h[j] = hh; l[j] = ll;
    }
    *(v8u*)(Khi + i) = h;
    *(v8u*)(Klo + i) = l;
}

// ---------------- prep: V -> V^T bf16 [bh][d][k] ----------------
__global__ __launch_bounds__(256) void prep_v(const float* __restrict__ V,
    unsigned short* __restrict__ VT)
{
    __shared__ float Ts[64][65];
    const int bh = blockIdx.x >> 4, kt = blockIdx.x & 15;
    const int t = threadIdx.x;
    {
        const int r = t >> 2, cs = (t & 3) << 4;
        const float* src = V + ((size_t)bh * Sn + (kt << 6) + r) * Dn + cs;
        const v4f a = __builtin_nontemporal_load((const v4f*)src);
        const v4f b = __builtin_nontemporal_load((const v4f*)src + 1);
        const v4f c = __builtin_nontemporal_load((const v4f*)src + 2);
        const v4f d = __builtin_nontemporal_load((const v4f*)src + 3);
        #pragma unroll
        for (int j = 0; j < 4; ++j) {
            Ts[r][cs + j]      = a[j];
            Ts[r][cs + 4 + j]  = b[j];
            Ts[r][cs + 8 + j]  = c[j];
            Ts[r][cs + 12 + j] = d[j];
        }
    }
    __syncthreads();
    {
        const int dd = t >> 2, ks = (t & 3) << 4;
        unsigned short* dst = VT + ((size_t)bh << 16) + ((size_t)dd << 10) + (kt << 6) + ks;
        v8u o0, o1;
        #pragma unroll
        for (int j = 0; j < 8; ++j) o0[j] = f2bf(Ts[ks + j][dd]);
        #pragma unroll
        for (int j = 0; j < 8; ++j) o1[j] = f2bf(Ts[ks + 8 + j][dd]);
        *(v8u*)dst = o0;
        *(v8u*)(dst + 8) = o1;
    }
}

// ---------------- prep: mask int32 -> bit-packed u64 words ----------------
__global__ __launch_bounds__(256) void prep_m(const int* __restrict__ M,
    unsigned long long* __restrict__ MW)
{
    const int NW = 2097152;   // 128*1024*1024 / 64
    const int lane = threadIdx.x & 63;
    const int wave = (blockIdx.x << 2) + (threadIdx.x >> 6);
    const int nwaves = gridDim.x << 2;
    for (int w0 = wave << 3; w0 < NW; w0 += nwaves << 3) {
        unsigned long long b[8];
        #pragma unroll
        for (int s = 0; s < 8; ++s) {
            const int v = __builtin_nontemporal_load(&M[((size_t)(w0 + s) << 6) + lane]);
            b[s] = __ballot(v != 0);
        }
        if (lane == 0) {
            ulonglong2* dst = (ulonglong2*)(MW + w0);
            ulonglong2 p0, p1, p2, p3;
            p0.x = b[0]; p0.y = b[1]; p1.x = b[2]; p1.y = b[3];
            p2.x = b[4]; p2.y = b[5]; p3.x = b[6]; p3.y = b[7];
            dst[0] = p0; dst[1] = p1; dst[2] = p2; dst[3] = p3;
        }
    }
}

// ---------------- fused attention: barrier-free loops, direct global frags ----
// Block: 16 q-rows, 4 waves, 4 blocks/CU (LDS = Ph only, 33 KB).
// Wave w touches ONLY K rows / VT rows [w*16, w*16+16) -> no cross-wave sharing
// -> no inner-loop barriers. 2-deep ping-pong prefetch covers L2 latency.
__global__ __launch_bounds__(256, 4) void fused_attn_d(
    const unsigned short* __restrict__ KhiG, const unsigned short* __restrict__ KloG,
    const unsigned short* __restrict__ VTG,  const float* __restrict__ Q,
    const unsigned long long* __restrict__ MW,
    float* __restrict__ attnO, float* __restrict__ ctxO)
{
    __shared__ unsigned short Ph[16][PH_LD];
    __shared__ float rsumW[4][16];
    __shared__ float invL[16];

    const int tid  = threadIdx.x;
    const int lane = tid & 63;
    const int w    = tid >> 6;
    const int fr   = lane & 15;
    const int g    = lane >> 4;

    // bijective XCD swizzle: all 64 q-blocks of one bh land on one XCD
    const int swz = ((blockIdx.x & 7) << 10) + (blockIdx.x >> 3);
    const int bh = swz >> 6;
    const int q0 = (swz & 63) << 4;

    const float* Qb = Q + (size_t)bh * Sn * Dn + (size_t)q0 * Dn;
    float*       Ab = attnO + (size_t)bh * Sn * Sn + (size_t)q0 * Sn;
    float*       Cb = ctxO  + (size_t)bh * Sn * Dn + (size_t)q0 * Dn;
    const unsigned long long* mwp = MW + ((size_t)bh << 14) + ((size_t)(q0 + fr) << 4);

    // Q B-fragments: global float4 + in-reg split (once per block)
    v8s qh0, qh1, ql0, ql1;
    {
        const float* qp = Qb + fr * Dn + (g << 3);
        float x0[8], x1[8];
        *(v4f*)&x0[0] = *(const v4f*)qp;
        *(v4f*)&x0[4] = *(const v4f*)(qp + 4);
        *(v4f*)&x1[0] = *(const v4f*)(qp + 32);
        *(v4f*)&x1[4] = *(const v4f*)(qp + 36);
        #pragma unroll
        for (int i = 0; i < 8; ++i) {
            unsigned short hh, ll;
            split2(x0[i], hh, ll); qh0[i] = (short)hh; ql0[i] = (short)ll;
            split2(x1[i], hh, ll); qh1[i] = (short)hh; ql1[i] = (short)ll;
        }
    }

    // per-lane K fragment base: row = kt*64 + w*16 + fr, d-chunk g*8 (+32)
    const unsigned short* khp = KhiG + ((size_t)bh << 16) + ((size_t)((w << 4) + fr) << 6) + (g << 3);
    const unsigned short* klp = KloG + ((size_t)bh << 16) + ((size_t)((w << 4) + fr) << 6) + (g << 3);
    const int sh = (w << 4) + (g << 2);

#define LDK(kt, h0, h1, l0, l1) do {                                     \
        const unsigned short* _p = khp + ((size_t)(kt) << 12);           \
        const unsigned short* _q = klp + ((size_t)(kt) << 12);           \
        h0 = *(const v8s*)_p;  h1 = *(const v8s*)(_p + 32);              \
        l0 = *(const v8s*)_q;  l1 = *(const v8s*)(_q + 32);              \
    } while (0)

#define STEPA(h0, h1, l0, l1, mwv, kt) do {                                        \
        v4f acc = {0.f, 0.f, 0.f, 0.f};                                            \
        acc = __builtin_amdgcn_mfma_f32_16x16x32_bf16(h0, qh0, acc, 0, 0, 0);      \
        acc = __builtin_amdgcn_mfma_f32_16x16x32_bf16(h1, qh1, acc, 0, 0, 0);      \
        acc = __builtin_amdgcn_mfma_f32_16x16x32_bf16(l0, qh0, acc, 0, 0, 0);      \
        acc = __builtin_amdgcn_mfma_f32_16x16x32_bf16(l1, qh1, acc, 0, 0, 0);      \
        acc = __builtin_amdgcn_mfma_f32_16x16x32_bf16(h0, ql0, acc, 0, 0, 0);      \
        acc = __builtin_amdgcn_mfma_f32_16x16x32_bf16(h1, ql1, acc, 0, 0, 0);      \
        const unsigned mb = (unsigned)((mwv) >> sh);                               \
        const float e0 = (mb & 1u) ? 1.0f : __expf(acc[0]);                        \
        const float e1 = (mb & 2u) ? 1.0f : __expf(acc[1]);                        \
        const float e2 = (mb & 4u) ? 1.0f : __expf(acc[2]);                        \
        const float e3 = (mb & 8u) ? 1.0f : __expf(acc[3]);                        \
        rs += (e0 + e1) + (e2 + e3);                                               \
        ushort4 pk;                                                                \
        pk.x = f2bf(e0); pk.y = f2bf(e1); pk.z = f2bf(e2); pk.w = f2bf(e3);        \
        *(ushort4*)&Ph[fr][((kt) << 6) + (w << 4) + (g << 2)] = pk;                \
    } while (0)

    float rs = 0.f;

    // ---- Phase A: barrier-free, 2-deep ping-pong prefetch ----
    {
        v8s ah0, ah1, al0, al1, bh0, bh1, bl0, bl1;
        LDK(0, ah0, ah1, al0, al1);
        LDK(1, bh0, bh1, bl0, bl1);
        unsigned long long mA = mwp[0], mB = mwp[1];
        for (int kt = 0; kt < 16; kt += 2) {
            const int k2 = (kt + 2 < 16) ? kt + 2 : kt;
            const int k3 = (kt + 3 < 16) ? kt + 3 : kt;
            v8s ch0, ch1, cl0, cl1, dh0, dh1, dl0, dl1;
            LDK(k2, ch0, ch1, cl0, cl1);
            LDK(k3, dh0, dh1, dl0, dl1);
            const unsigned long long mC = mwp[k2];
            const unsigned long long mD = mwp[k3];
            STEPA(ah0, ah1, al0, al1, mA, kt);
            STEPA(bh0, bh1, bl0, bl1, mB, kt + 1);
            ah0 = ch0; ah1 = ch1; al0 = cl0; al1 = cl1; mA = mC;
            bh0 = dh0; bh1 = dh1; bl0 = dl0; bl1 = dl1; mB = mD;
        }
    }

    // ---- row-sum reduce (the only 2 barriers in the kernel) ----
    rs += __shfl_xor(rs, 16);
    rs += __shfl_xor(rs, 32);
    if (g == 0) rsumW[w][fr] = rs;
    __syncthreads();                       // Ph + rsumW visible
    if (tid < 16) {
        const float s = rsumW[0][tid] + rsumW[1][tid] + rsumW[2][tid] + rsumW[3][tid];
        invL[tid] = 1.0f / s;
    }
    __syncthreads();                       // invL visible

    // ---- write normalized attn early (NT stream goes out under Phase B) ----
    {
        const int qq = tid >> 4, ii = tid & 15;
        const float inv = invL[qq];
        float* arow = Ab + (size_t)qq * Sn;
        #pragma unroll
        for (int c = 0; c < 16; ++c) {
            const int k0 = (c << 6) + (ii << 2);
            const ushort4 p = *(const ushort4*)&Ph[qq][k0];
            v4f o;
            o[0] = bf2f(p.x) * inv; o[1] = bf2f(p.y) * inv;
            o[2] = bf2f(p.z) * inv; o[3] = bf2f(p.w) * inv;
            __builtin_nontemporal_store(o, (v4f*)(arow + k0));
        }
    }

    // ---- Phase B: ctx = (P V) * inv, barrier-free, 2-deep prefetch ----
    const unsigned short* vtp = VTG + ((size_t)bh << 16) + ((size_t)((w << 4) + fr) << 10) + (g << 3);

#define LDV(kt, v0, v1) do {                                             \
        const unsigned short* _p = vtp + ((kt) << 6);                    \
        v0 = *(const v8s*)_p;  v1 = *(const v8s*)(_p + 32);              \
    } while (0)

#define STEPB(v0, v1, kt) do {                                                     \
        const v8s a0 = *(const v8s*)&Ph[fr][((kt) << 6) + (g << 3)];               \
        const v8s a1 = *(const v8s*)&Ph[fr][((kt) << 6) + 32 + (g << 3)];          \
        accp = __builtin_amdgcn_mfma_f32_16x16x32_bf16(a0, v0, accp, 0, 0, 0);     \
        accp = __builtin_amdgcn_mfma_f32_16x16x32_bf16(a1, v1, accp, 0, 0, 0);     \
    } while (0)

    const int dcol = (w << 4) + fr;
    v4f accp = {0.f, 0.f, 0.f, 0.f};
    {
        v8s va0, va1, vb0, vb1;
        LDV(0, va0, va1);
        LDV(1, vb0, vb1);
        for (int kt = 0; kt < 16; kt += 2) {
            const int k2 = (kt + 2 < 16) ? kt + 2 : kt;
            const int k3 = (kt + 3 < 16) ? kt + 3 : kt;
            v8s vc0, vc1, vd0, vd1;
            LDV(k2, vc0, vc1);
            LDV(k3, vd0, vd1);
            STEPB(va0, va1, kt);
            STEPB(vb0, vb1, kt + 1);
            va0 = vc0; va1 = vc1;
            vb0 = vd0; vb1 = vd1;
        }
    }
    #pragma unroll
    for (int r = 0; r < 4; ++r) {
        const int q = (g << 2) + r;
        __builtin_nontemporal_store(accp[r] * invL[q], &Cb[(size_t)q * Dn + dcol]);
    }
#undef LDK
#undef STEPA
#undef LDV
#undef STEPB
}

// ---------------- fallback (round-3 kernel, in-kernel split) ----------------
__global__ __launch_bounds__(256, 3) void fused_attn_fb(
    const float* __restrict__ Q, const float* __restrict__ K,
    const float* __restrict__ V, const int* __restrict__ M,
    float* __restrict__ attnO, float* __restrict__ ctxO)
{
    __shared__ unsigned short Ph[16][1048];
    __shared__ __align__(16) unsigned short Kraw[2 * 64 * K_LD];
    __shared__ float rsumW[4][16];
    __shared__ float invL[16];

    unsigned short (*Khi)[K_LD] = (unsigned short (*)[K_LD])Kraw;
    unsigned short (*Klo)[K_LD] = (unsigned short (*)[K_LD])(Kraw + 64 * K_LD);
    unsigned short (*Vt)[V_LD]  = (unsigned short (*)[V_LD])Kraw;

    const int tid  = threadIdx.x;
    const int lane = tid & 63;
    const int w    = tid >> 6;
    const int fr   = lane & 15;
    const int g    = lane >> 4;

    const int bh = blockIdx.x >> 6;
    const int q0 = (blockIdx.x & 63) << 4;

    const float* Qb = Q + (size_t)bh * Sn * Dn + (size_t)q0 * Dn;
    const float* Kb = K + (size_t)bh * Sn * Dn;
    const float* Vb = V + (size_t)bh * Sn * Dn;
    const int*   Mb = M + (size_t)bh * Sn * Sn + (size_t)q0 * Sn;
    float*       Ab = attnO + (size_t)bh * Sn * Sn + (size_t)q0 * Sn;
    float*       Cb = ctxO  + (size_t)bh * Sn * Dn + (size_t)q0 * Dn;

    v8s qh0, qh1, ql0, ql1;
    {
        const float* qp = Qb + fr * Dn + (g << 3);
        float x0[8], x1[8];
        *(v4f*)&x0[0] = *(const v4f*)qp;
        *(v4f*)&x0[4] = *(const v4f*)(qp + 4);
        *(v4f*)&x1[0] = *(const v4f*)(qp + 32);
        *(v4f*)&x1[4] = *(const v4f*)(qp + 36);
        #pragma unroll
        for (int i = 0; i < 8; ++i) {
            unsigned short hh, ll;
            split2(x0[i], hh, ll); qh0[i] = (short)hh; ql0[i] = (short)ll;
            split2(x1[i], hh, ll); qh1[i] = (short)hh; ql1[i] = (short)ll;
        }
    }

    const int srow = tid >> 4;
    const int sc4  = (tid & 15) << 2;

    const int* mp = Mb + (size_t)fr * Sn + (w << 4) + (g << 2);
    v4i mv = *(const v4i*)mp;

    v4f ka[4];
    #pragma unroll
    for (int i = 0; i < 4; ++i)
        ka[i] = *(const v4f*)(Kb + (size_t)(srow + (i << 4)) * Dn + sc4);

    float rs = 0.f;

    for (int kt = 0; kt < 16; ++kt) {
        __syncthreads();
        v4f kb[4];
        if (kt < 15) {
            const float* kn = Kb + (size_t)((kt + 1) << 6) * Dn;
            #pragma unroll
            for (int i = 0; i < 4; ++i)
                kb[i] = *(const v4f*)(kn + (size_t)(srow + (i << 4)) * Dn + sc4);
        }
        v4i mnext = mv;
        if (kt < 15) mnext = *(const v4i*)(mp + ((kt + 1) << 6));

        #pragma unroll
        for (int i = 0; i < 4; ++i) {
            const int row = srow + (i << 4);
            ushort4 hv, lv;
            split2(ka[i][0], hv.x, lv.x); split2(ka[i][1], hv.y, lv.y);
            split2(ka[i][2], hv.z, lv.z); split2(ka[i][3], hv.w, lv.w);
            *(ushort4*)&Khi[row][sc4] = hv;
            *(ushort4*)&Klo[row][sc4] = lv;
        }
        __syncthreads();

        const int krow = (w << 4) + fr;
        const v8s kh0 = *(const v8s*)&Khi[krow][(g << 3)];
        const v8s kh1 = *(const v8s*)&Khi[krow][32 + (g << 3)];
        const v8s kl0 = *(const v8s*)&Klo[krow][(g << 3)];
        const v8s kl1 = *(const v8s*)&Klo[krow][32 + (g << 3)];

        v4f acc = {0.f, 0.f, 0.f, 0.f};
        acc = __builtin_amdgcn_mfma_f32_16x16x32_bf16(kh0, qh0, acc, 0, 0, 0);
        acc = __builtin_amdgcn_mfma_f32_16x16x32_bf16(kh1, qh1, acc, 0, 0, 0);
        acc = __builtin_amdgcn_mfma_f32_16x16x32_bf16(kl0, qh0, acc, 0, 0, 0);
        acc = __builtin_amdgcn_mfma_f32_16x16x32_bf16(kl1, qh1, acc, 0, 0, 0);
        acc = __builtin_amdgcn_mfma_f32_16x16x32_bf16(kh0, ql0, acc, 0, 0, 0);
        acc = __builtin_amdgcn_mfma_f32_16x16x32_bf16(kh1, ql1, acc, 0, 0, 0);

        const float e0 = mv[0] ? 1.0f : __expf(acc[0]);
        const float e1 = mv[1] ? 1.0f : __expf(acc[1]);
        const float e2 = mv[2] ? 1.0f : __expf(acc[2]);
        const float e3 = mv[3] ? 1.0f : __expf(acc[3]);
        rs += (e0 + e1) + (e2 + e3);
        ushort4 pk;
        pk.x = f2bf(e0); pk.y = f2bf(e1); pk.z = f2bf(e2); pk.w = f2bf(e3);
        *(ushort4*)&Ph[fr][(kt << 6) + (w << 4) + (g << 2)] = pk;

        mv = mnext;
        #pragma unroll
        for (int i = 0; i < 4; ++i) ka[i] = kb[i];
    }

    rs += __shfl_xor(rs, 16);
    rs += __shfl_xor(rs, 32);
    if (g == 0) rsumW[w][fr] = rs;
    __syncthreads();
    if (tid < 16) {
        const float s = rsumW[0][tid] + rsumW[1][tid] + rsumW[2][tid] + rsumW[3][tid];
        invL[tid] = 1.0f / s;
    }
    __syncthreads();

    const int dcol = (w << 4) + fr;
    v4f va[4];
    #pragma unroll
    for (int i = 0; i < 4; ++i)
        va[i] = *(const v4f*)(Vb + (size_t)(srow + (i << 4)) * Dn + sc4);

    v4f accp = {0.f, 0.f, 0.f, 0.f};
    for (int kt = 0; kt < 16; ++kt) {
        __syncthreads();
        v4f vb[4];
        if (kt < 15) {
            const float* vn = Vb + (size_t)((kt + 1) << 6) * Dn;
            #pragma unroll
            for (int i = 0; i < 4; ++i)
                vb[i] = *(const v4f*)(vn + (size_t)(srow + (i << 4)) * Dn + sc4);
        }
        #pragma unroll
        for (int i = 0; i < 4; ++i) {
            const int row = srow + (i << 4);
            Vt[sc4 + 0][row] = f2bf(va[i][0]);
            Vt[sc4 + 1][row] = f2bf(va[i][1]);
            Vt[sc4 + 2][row] = f2bf(va[i][2]);
            Vt[sc4 + 3][row] = f2bf(va[i][3]);
        }
        __syncthreads();

        #pragma unroll
        for (int c = 0; c < 2; ++c) {
            const int kc = (kt << 6) + (c << 5);
            const v8s a = *(const v8s*)&Ph[fr][kc + (g << 3)];
            const v8s b = *(const v8s*)&Vt[dcol][(c << 5) + (g << 3)];
            accp = __builtin_amdgcn_mfma_f32_16x16x32_bf16(a, b, accp, 0, 0, 0);
        }
        #pragma unroll
        for (int i = 0; i < 4; ++i) va[i] = vb[i];
    }
    #pragma unroll
    for (int r = 0; r < 4; ++r) {
        const int q = (g << 2) + r;
        Cb[(size_t)q * Dn + dcol] = accp[r] * invL[q];
    }

    {
        const int qq = tid >> 4, ii = tid & 15;
        const float inv = invL[qq];
        float* arow = Ab + (size_t)qq * Sn;
        #pragma unroll
        for (int c = 0; c < 16; ++c) {
            const int k0 = (c << 6) + (ii << 2);
            const ushort4 p = *(const ushort4*)&Ph[qq][k0];
            v4f o;
            o[0] = bf2f(p.x) * inv; o[1] = bf2f(p.y) * inv;
            o[2] = bf2f(p.z) * inv; o[3] = bf2f(p.w) * inv;
            *(v4f*)(arow + k0) = o;
        }
    }
}

extern "C" void kernel_launch(void* const* d_in, const int* in_sizes, int n_in,
                              void* d_out, int out_size, void* d_ws, size_t ws_size,
                              hipStream_t stream) {
    const float* Q    = (const float*)d_in[0];
    const float* K    = (const float*)d_in[1];
    const float* V    = (const float*)d_in[2];
    const int*   mask = (const int*)d_in[3];

    float* ctx  = (float*)d_out;                           // (B,H,S,D)
    float* attn = (float*)d_out + (size_t)128 * Sn * Dn;   // (B,H,S,S)

    const size_t NELEM = (size_t)128 * Sn * Dn;            // 8,388,608
    const size_t MWORDS = (size_t)128 * Sn * 16;           // 2,097,152 u64
    const size_t NEED  = NELEM * 2 * 3 + MWORDS * 8;       // 50.3MB + 16.8MB

    if (ws_size >= NEED) {
        unsigned short* Khi = (unsigned short*)d_ws;
        unsigned short* Klo = Khi + NELEM;
        unsigned short* VT  = Klo + NELEM;
        unsigned long long* MWp = (unsigned long long*)((char*)d_ws + NELEM * 2 * 3);
        prep_k<<<4096, 256, 0, stream>>>(K, Khi, Klo);
        prep_v<<<2048, 256, 0, stream>>>(V, VT);
        prep_m<<<2048, 256, 0, stream>>>(mask, MWp);
        fused_attn_d<<<128 * 64, 256, 0, stream>>>(Khi, Klo, VT, Q, MWp, attn, ctx);
    } else {
        fused_attn_fb<<<128 * 64, 256, 0, stream>>>(Q, K, V, mask, attn, ctx);
    }
}

// Round 9
// 344.056 us; speedup vs baseline: 1.5209x; 1.5209x over previous
//
#include <hip/hip_runtime.h>

#define Sn 1024
#define Dn 64
#define PH_LD 1032   // ushorts/row: 516 dw ≡ 4 (mod 32) -> balanced b64 write / b128 read / b64 read
#define K_LD 72
#define V_LD 72

typedef short v8s __attribute__((ext_vector_type(8)));
typedef unsigned short v8u __attribute__((ext_vector_type(8)));
typedef float v4f __attribute__((ext_vector_type(4)));
typedef int   v4i __attribute__((ext_vector_type(4)));

// Raw barrier + counted-wait primitives (T3/T4): lgkm-only flush before the
// barrier so global prefetch loads SURVIVE it (no vmcnt(0) drain per iter).
#define LGKM0()  asm volatile("s_waitcnt lgkmcnt(0)" ::: "memory")
#define SBAR()   do { asm volatile("" ::: "memory"); __builtin_amdgcn_s_barrier(); \
                      __builtin_amdgcn_sched_barrier(0); } while (0)

__device__ __forceinline__ unsigned short f2bf(float x) {
    union { float f; unsigned u; } v; v.f = x;
    return (unsigned short)((v.u + 0x7FFFu + ((v.u >> 16) & 1u)) >> 16);
}
__device__ __forceinline__ float bf2f(unsigned short h) {
    union { float f; unsigned u; } v; v.u = ((unsigned)h) << 16;
    return v.f;
}
__device__ __forceinline__ void split2(float x, unsigned short& h, unsigned short& l) {
    unsigned short hs = f2bf(x);
    h = hs; l = f2bf(x - bf2f(hs));
}

// ---------------- prep: K -> Khi/Klo bf16 (flat) ----------------
__global__ __launch_bounds__(256) void prep_k(const float* __restrict__ K,
    unsigned short* __restrict__ Khi, unsigned short* __restrict__ Klo)
{
    const size_t i = (((size_t)blockIdx.x << 8) + threadIdx.x) << 3;
    const v4f x0 = __builtin_nontemporal_load((const v4f*)(K + i));
    const v4f x1 = __builtin_nontemporal_load((const v4f*)(K + i + 4));
    float x[8];
    *(v4f*)&x[0] = x0;
    *(v4f*)&x[4] = x1;
    v8u h, l;
    #pragma unroll
    for (int j = 0; j < 8; ++j) {
        unsigned short hh, ll;
        split2(x[j], hh, ll);
        h[j] = hh; l[j] = ll;
    }
    *(v8u*)(Khi + i) = h;
    *(v8u*)(Klo + i) = l;
}

// ---------------- prep: V -> V^T bf16 [bh][d][k] ----------------
__global__ __launch_bounds__(256) void prep_v(const float* __restrict__ V,
    unsigned short* __restrict__ VT)
{
    __shared__ float Ts[64][65];
    const int bh = blockIdx.x >> 4, kt = blockIdx.x & 15;
    const int t = threadIdx.x;
    {
        const int r = t >> 2, cs = (t & 3) << 4;
        const float* src = V + ((size_t)bh * Sn + (kt << 6) + r) * Dn + cs;
        const v4f a = __builtin_nontemporal_load((const v4f*)src);
        const v4f b = __builtin_nontemporal_load((const v4f*)src + 1);
        const v4f c = __builtin_nontemporal_load((const v4f*)src + 2);
        const v4f d = __builtin_nontemporal_load((const v4f*)src + 3);
        #pragma unroll
        for (int j = 0; j < 4; ++j) {
            Ts[r][cs + j]      = a[j];
            Ts[r][cs + 4 + j]  = b[j];
            Ts[r][cs + 8 + j]  = c[j];
            Ts[r][cs + 12 + j] = d[j];
        }
    }
    __syncthreads();
    {
        const int dd = t >> 2, ks = (t & 3) << 4;
        unsigned short* dst = VT + ((size_t)bh << 16) + ((size_t)dd << 10) + (kt << 6) + ks;
        v8u o0, o1;
        #pragma unroll
        for (int j = 0; j < 8; ++j) o0[j] = f2bf(Ts[ks + j][dd]);
        #pragma unroll
        for (int j = 0; j < 8; ++j) o1[j] = f2bf(Ts[ks + 8 + j][dd]);
        *(v8u*)dst = o0;
        *(v8u*)(dst + 8) = o1;
    }
}

// ---------------- prep: mask int32 -> bit-packed u64 words ----------------
__global__ __launch_bounds__(256) void prep_m(const int* __restrict__ M,
    unsigned long long* __restrict__ MW)
{
    const int NW = 2097152;   // 128*1024*1024 / 64
    const int lane = threadIdx.x & 63;
    const int wave = (blockIdx.x << 2) + (threadIdx.x >> 6);
    const int nwaves = gridDim.x << 2;
    for (int w0 = wave << 3; w0 < NW; w0 += nwaves << 3) {
        unsigned long long b[8];
        #pragma unroll
        for (int s = 0; s < 8; ++s) {
            const int v = __builtin_nontemporal_load(&M[((size_t)(w0 + s) << 6) + lane]);
            b[s] = __ballot(v != 0);
        }
        if (lane == 0) {
            ulonglong2* dst = (ulonglong2*)(MW + w0);
            ulonglong2 p0, p1, p2, p3;
            p0.x = b[0]; p0.y = b[1]; p1.x = b[2]; p1.y = b[3];
            p2.x = b[4]; p2.y = b[5]; p3.x = b[6]; p3.y = b[7];
            dst[0] = p0; dst[1] = p1; dst[2] = p2; dst[3] = p3;
        }
    }
}

// ---------------- fused attention: LDS-staged, RAW barriers (loads survive) ----
// Block: 16 q-rows, 4 waves, 3 blocks/CU. In-loop barriers are raw s_barrier
// with lgkm-only flush -> K/V/mask prefetch stays in flight across them.
__global__ __launch_bounds__(256, 3) void fused_attn_r(
    const unsigned short* __restrict__ KhiG, const unsigned short* __restrict__ KloG,
    const unsigned short* __restrict__ VTG,  const float* __restrict__ Q,
    const unsigned long long* __restrict__ MW,
    float* __restrict__ attnO, float* __restrict__ ctxO)
{
    __shared__ unsigned short Ph[16][PH_LD];
    __shared__ __align__(16) unsigned short Kraw[2 * 64 * K_LD];
    __shared__ float rsumW[4][16];
    __shared__ float invL[16];

    unsigned short (*Khi)[K_LD] = (unsigned short (*)[K_LD])Kraw;
    unsigned short (*Klo)[K_LD] = (unsigned short (*)[K_LD])(Kraw + 64 * K_LD);
    unsigned short (*Vt)[V_LD]  = (unsigned short (*)[V_LD])Kraw;

    const int tid  = threadIdx.x;
    const int lane = tid & 63;
    const int w    = tid >> 6;
    const int fr   = lane & 15;
    const int g    = lane >> 4;

    // bijective XCD swizzle: all 64 q-blocks of one bh land on one XCD
    const int swz = ((blockIdx.x & 7) << 10) + (blockIdx.x >> 3);
    const int bh = swz >> 6;
    const int q0 = (swz & 63) << 4;

    const float* Qb = Q + (size_t)bh * Sn * Dn + (size_t)q0 * Dn;
    float*       Ab = attnO + (size_t)bh * Sn * Sn + (size_t)q0 * Sn;
    float*       Cb = ctxO  + (size_t)bh * Sn * Dn + (size_t)q0 * Dn;
    const unsigned short* KhiB = KhiG + ((size_t)bh << 16);
    const unsigned short* KloB = KloG + ((size_t)bh << 16);
    const unsigned short* VTB  = VTG  + ((size_t)bh << 16);
    const unsigned long long* mwp = MW + ((size_t)bh << 14) + ((size_t)(q0 + fr) << 4);

    // Q B-fragments: global float4 + in-reg split (once per block)
    v8s qh0, qh1, ql0, ql1;
    {
        const float* qp = Qb + fr * Dn + (g << 3);
        float x0[8], x1[8];
        *(v4f*)&x0[0] = *(const v4f*)qp;
        *(v4f*)&x0[4] = *(const v4f*)(qp + 4);
        *(v4f*)&x1[0] = *(const v4f*)(qp + 32);
        *(v4f*)&x1[4] = *(const v4f*)(qp + 36);
        #pragma unroll
        for (int i = 0; i < 8; ++i) {
            unsigned short hh, ll;
            split2(x0[i], hh, ll); qh0[i] = (short)hh; ql0[i] = (short)ll;
            split2(x1[i], hh, ll); qh1[i] = (short)hh; ql1[i] = (short)ll;
        }
    }

    const int srow = tid >> 2;          // 0..63
    const int sseg = (tid & 3) << 4;    // ushort col: 0/16/32/48
    const int sh   = (w << 4) + (g << 2);
    const int krow = (w << 4) + fr;

    unsigned long long mw = mwp[0];

    // preload K tile 0 (bf16 hi/lo) into regs
    uint4 ch0, ch1, cl0, cl1;
    {
        const uint4* ph = (const uint4*)(KhiB + (size_t)srow * Dn + sseg);
        const uint4* pl = (const uint4*)(KloB + (size_t)srow * Dn + sseg);
        ch0 = ph[0]; ch1 = ph[1]; cl0 = pl[0]; cl1 = pl[1];
    }

    float rs = 0.f;

    // ---- Phase A: raw barriers, prefetch survives ----
    for (int kt = 0; kt < 16; ++kt) {
        SBAR();   // all waves done reading tile kt-1 frags (lgkm-complete via MFMA waits)
        *(uint4*)&Khi[srow][sseg]     = ch0;
        *(uint4*)&Khi[srow][sseg + 8] = ch1;
        *(uint4*)&Klo[srow][sseg]     = cl0;
        *(uint4*)&Klo[srow][sseg + 8] = cl1;

        unsigned long long mnext = mw;
        if (kt < 15) {
            const uint4* ph = (const uint4*)(KhiB + (size_t)((kt + 1) * 64 + srow) * Dn + sseg);
            const uint4* pl = (const uint4*)(KloB + (size_t)((kt + 1) * 64 + srow) * Dn + sseg);
            ch0 = ph[0]; ch1 = ph[1]; cl0 = pl[0]; cl1 = pl[1];   // in flight across barrier
            mnext = mwp[kt + 1];
        }
        __builtin_amdgcn_sched_barrier(0);
        LGKM0();  // my ds_writes visible (does NOT drain vmcnt)
        SBAR();

        const v8s kh0 = *(const v8s*)&Khi[krow][(g << 3)];
        const v8s kh1 = *(const v8s*)&Khi[krow][32 + (g << 3)];
        const v8s kl0 = *(const v8s*)&Klo[krow][(g << 3)];
        const v8s kl1 = *(const v8s*)&Klo[krow][32 + (g << 3)];

        v4f acc = {0.f, 0.f, 0.f, 0.f};
        __builtin_amdgcn_s_setprio(1);
        acc = __builtin_amdgcn_mfma_f32_16x16x32_bf16(kh0, qh0, acc, 0, 0, 0);
        acc = __builtin_amdgcn_mfma_f32_16x16x32_bf16(kh1, qh1, acc, 0, 0, 0);
        acc = __builtin_amdgcn_mfma_f32_16x16x32_bf16(kl0, qh0, acc, 0, 0, 0);
        acc = __builtin_amdgcn_mfma_f32_16x16x32_bf16(kl1, qh1, acc, 0, 0, 0);
        acc = __builtin_amdgcn_mfma_f32_16x16x32_bf16(kh0, ql0, acc, 0, 0, 0);
        acc = __builtin_amdgcn_mfma_f32_16x16x32_bf16(kh1, ql1, acc, 0, 0, 0);
        __builtin_amdgcn_s_setprio(0);

        const unsigned mb = (unsigned)(mw >> sh);
        const float e0 = (mb & 1u) ? 1.0f : __expf(acc[0]);
        const float e1 = (mb & 2u) ? 1.0f : __expf(acc[1]);
        const float e2 = (mb & 4u) ? 1.0f : __expf(acc[2]);
        const float e3 = (mb & 8u) ? 1.0f : __expf(acc[3]);
        rs += (e0 + e1) + (e2 + e3);
        ushort4 pk;
        pk.x = f2bf(e0); pk.y = f2bf(e1); pk.z = f2bf(e2); pk.w = f2bf(e3);
        *(ushort4*)&Ph[fr][(kt << 6) + (w << 4) + (g << 2)] = pk;

        mw = mnext;
    }

    // preload V tile 0 early — survives the raw rowsum barriers below
    uint4 cv0, cv1;
    {
        const uint4* pv = (const uint4*)(VTB + ((size_t)srow << 10) + sseg);
        cv0 = pv[0]; cv1 = pv[1];
    }

    // ---- row-sum reduce (raw barriers, lgkm flush covers Ph + rsumW) ----
    rs += __shfl_xor(rs, 16);
    rs += __shfl_xor(rs, 32);
    if (g == 0) rsumW[w][fr] = rs;
    __builtin_amdgcn_sched_barrier(0);
    LGKM0();
    SBAR();
    if (tid < 16) {
        const float s = rsumW[0][tid] + rsumW[1][tid] + rsumW[2][tid] + rsumW[3][tid];
        invL[tid] = 1.0f / s;
    }
    __builtin_amdgcn_sched_barrier(0);
    LGKM0();
    SBAR();

    // ---- write normalized attn early (NT stream drains under Phase B) ----
    {
        const int qq = tid >> 4, ii = tid & 15;
        const float inv = invL[qq];
        float* arow = Ab + (size_t)qq * Sn;
        #pragma unroll
        for (int c = 0; c < 16; ++c) {
            const int k0 = (c << 6) + (ii << 2);
            const ushort4 p = *(const ushort4*)&Ph[qq][k0];
            v4f o;
            o[0] = bf2f(p.x) * inv; o[1] = bf2f(p.y) * inv;
            o[2] = bf2f(p.z) * inv; o[3] = bf2f(p.w) * inv;
            __builtin_nontemporal_store(o, (v4f*)(arow + k0));
        }
    }

    // ---- Phase B: ctx = (P V) * inv, raw barriers ----
    const int dcol = (w << 4) + fr;
    v4f accp = {0.f, 0.f, 0.f, 0.f};
    for (int kt = 0; kt < 16; ++kt) {
        SBAR();   // prev Vt frag reads done; attn-write Ph reads done (1st iter)
        *(uint4*)&Vt[srow][sseg]     = cv0;
        *(uint4*)&Vt[srow][sseg + 8] = cv1;
        if (kt < 15) {
            const uint4* pv = (const uint4*)(VTB + ((size_t)srow << 10) + ((kt + 1) << 6) + sseg);
            cv0 = pv[0]; cv1 = pv[1];   // in flight across barrier
        }
        __builtin_amdgcn_sched_barrier(0);
        LGKM0();
        SBAR();

        const v8s a0 = *(const v8s*)&Ph[fr][(kt << 6) + (g << 3)];
        const v8s a1 = *(const v8s*)&Ph[fr][(kt << 6) + 32 + (g << 3)];
        const v8s b0 = *(const v8s*)&Vt[dcol][(g << 3)];
        const v8s b1 = *(const v8s*)&Vt[dcol][32 + (g << 3)];
        __builtin_amdgcn_s_setprio(1);
        accp = __builtin_amdgcn_mfma_f32_16x16x32_bf16(a0, b0, accp, 0, 0, 0);
        accp = __builtin_amdgcn_mfma_f32_16x16x32_bf16(a1, b1, accp, 0, 0, 0);
        __builtin_amdgcn_s_setprio(0);
    }
    #pragma unroll
    for (int r = 0; r < 4; ++r) {
        const int q = (g << 2) + r;
        __builtin_nontemporal_store(accp[r] * invL[q], &Cb[(size_t)q * Dn + dcol]);
    }
}

// ---------------- fallback (round-3 kernel, in-kernel split) ----------------
__global__ __launch_bounds__(256, 3) void fused_attn_fb(
    const float* __restrict__ Q, const float* __restrict__ K,
    const float* __restrict__ V, const int* __restrict__ M,
    float* __restrict__ attnO, float* __restrict__ ctxO)
{
    __shared__ unsigned short Ph[16][1048];
    __shared__ __align__(16) unsigned short Kraw[2 * 64 * K_LD];
    __shared__ float rsumW[4][16];
    __shared__ float invL[16];

    unsigned short (*Khi)[K_LD] = (unsigned short (*)[K_LD])Kraw;
    unsigned short (*Klo)[K_LD] = (unsigned short (*)[K_LD])(Kraw + 64 * K_LD);
    unsigned short (*Vt)[V_LD]  = (unsigned short (*)[V_LD])Kraw;

    const int tid  = threadIdx.x;
    const int lane = tid & 63;
    const int w    = tid >> 6;
    const int fr   = lane & 15;
    const int g    = lane >> 4;

    const int bh = blockIdx.x >> 6;
    const int q0 = (blockIdx.x & 63) << 4;

    const float* Qb = Q + (size_t)bh * Sn * Dn + (size_t)q0 * Dn;
    const float* Kb = K + (size_t)bh * Sn * Dn;
    const float* Vb = V + (size_t)bh * Sn * Dn;
    const int*   Mb = M + (size_t)bh * Sn * Sn + (size_t)q0 * Sn;
    float*       Ab = attnO + (size_t)bh * Sn * Sn + (size_t)q0 * Sn;
    float*       Cb = ctxO  + (size_t)bh * Sn * Dn + (size_t)q0 * Dn;

    v8s qh0, qh1, ql0, ql1;
    {
        const float* qp = Qb + fr * Dn + (g << 3);
        float x0[8], x1[8];
        *(v4f*)&x0[0] = *(const v4f*)qp;
        *(v4f*)&x0[4] = *(const v4f*)(qp + 4);
        *(v4f*)&x1[0] = *(const v4f*)(qp + 32);
        *(v4f*)&x1[4] = *(const v4f*)(qp + 36);
        #pragma unroll
        for (int i = 0; i < 8; ++i) {
            unsigned short hh, ll;
            split2(x0[i], hh, ll); qh0[i] = (short)hh; ql0[i] = (short)ll;
            split2(x1[i], hh, ll); qh1[i] = (short)hh; ql1[i] = (short)ll;
        }
    }

    const int srow = tid >> 4;
    const int sc4  = (tid & 15) << 2;

    const int* mp = Mb + (size_t)fr * Sn + (w << 4) + (g << 2);
    v4i mv = *(const v4i*)mp;

    v4f ka[4];
    #pragma unroll
    for (int i = 0; i < 4; ++i)
        ka[i] = *(const v4f*)(Kb + (size_t)(srow + (i << 4)) * Dn + sc4);

    float rs = 0.f;

    for (int kt = 0; kt < 16; ++kt) {
        __syncthreads();
        v4f kb[4];
        if (kt < 15) {
            const float* kn = Kb + (size_t)((kt + 1) << 6) * Dn;
            #pragma unroll
            for (int i = 0; i < 4; ++i)
                kb[i] = *(const v4f*)(kn + (size_t)(srow + (i << 4)) * Dn + sc4);
        }
        v4i mnext = mv;
        if (kt < 15) mnext = *(const v4i*)(mp + ((kt + 1) << 6));

        #pragma unroll
        for (int i = 0; i < 4; ++i) {
            const int row = srow + (i << 4);
            ushort4 hv, lv;
            split2(ka[i][0], hv.x, lv.x); split2(ka[i][1], hv.y, lv.y);
            split2(ka[i][2], hv.z, lv.z); split2(ka[i][3], hv.w, lv.w);
            *(ushort4*)&Khi[row][sc4] = hv;
            *(ushort4*)&Klo[row][sc4] = lv;
        }
        __syncthreads();

        const int krow = (w << 4) + fr;
        const v8s kh0 = *(const v8s*)&Khi[krow][(g << 3)];
        const v8s kh1 = *(const v8s*)&Khi[krow][32 + (g << 3)];
        const v8s kl0 = *(const v8s*)&Klo[krow][(g << 3)];
        const v8s kl1 = *(const v8s*)&Klo[krow][32 + (g << 3)];

        v4f acc = {0.f, 0.f, 0.f, 0.f};
        acc = __builtin_amdgcn_mfma_f32_16x16x32_bf16(kh0, qh0, acc, 0, 0, 0);
        acc = __builtin_amdgcn_mfma_f32_16x16x32_bf16(kh1, qh1, acc, 0, 0, 0);
        acc = __builtin_amdgcn_mfma_f32_16x16x32_bf16(kl0, qh0, acc, 0, 0, 0);
        acc = __builtin_amdgcn_mfma_f32_16x16x32_bf16(kl1, qh1, acc, 0, 0, 0);
        acc = __builtin_amdgcn_mfma_f32_16x16x32_bf16(kh0, ql0, acc, 0, 0, 0);
        acc = __builtin_amdgcn_mfma_f32_16x16x32_bf16(kh1, ql1, acc, 0, 0, 0);

        const float e0 = mv[0] ? 1.0f : __expf(acc[0]);
        const float e1 = mv[1] ? 1.0f : __expf(acc[1]);
        const float e2 = mv[2] ? 1.0f : __expf(acc[2]);
        const float e3 = mv[3] ? 1.0f : __expf(acc[3]);
        rs += (e0 + e1) + (e2 + e3);
        ushort4 pk;
        pk.x = f2bf(e0); pk.y = f2bf(e1); pk.z = f2bf(e2); pk.w = f2bf(e3);
        *(ushort4*)&Ph[fr][(kt << 6) + (w << 4) + (g << 2)] = pk;

        mv = mnext;
        #pragma unroll
        for (int i = 0; i < 4; ++i) ka[i] = kb[i];
    }

    rs += __shfl_xor(rs, 16);
    rs += __shfl_xor(rs, 32);
    if (g == 0) rsumW[w][fr] = rs;
    __syncthreads();
    if (tid < 16) {
        const float s = rsumW[0][tid] + rsumW[1][tid] + rsumW[2][tid] + rsumW[3][tid];
        invL[tid] = 1.0f / s;
    }
    __syncthreads();

    const int dcol = (w << 4) + fr;
    v4f va[4];
    #pragma unroll
    for (int i = 0; i < 4; ++i)
        va[i] = *(const v4f*)(Vb + (size_t)(srow + (i << 4)) * Dn + sc4);

    v4f accp = {0.f, 0.f, 0.f, 0.f};
    for (int kt = 0; kt < 16; ++kt) {
        __syncthreads();
        v4f vb[4];
        if (kt < 15) {
            const float* vn = Vb + (size_t)((kt + 1) << 6) * Dn;
            #pragma unroll
            for (int i = 0; i < 4; ++i)
                vb[i] = *(const v4f*)(vn + (size_t)(srow + (i << 4)) * Dn + sc4);
        }
        #pragma unroll
        for (int i = 0; i < 4; ++i) {
            const int row = srow + (i << 4);
            Vt[sc4 + 0][row] = f2bf(va[i][0]);
            Vt[sc4 + 1][row] = f2bf(va[i][1]);
            Vt[sc4 + 2][row] = f2bf(va[i][2]);
            Vt[sc4 + 3][row] = f2bf(va[i][3]);
        }
        __syncthreads();

        #pragma unroll
        for (int c = 0; c < 2; ++c) {
            const int kc = (kt << 6) + (c << 5);
            const v8s a = *(const v8s*)&Ph[fr][kc + (g << 3)];
            const v8s b = *(const v8s*)&Vt[dcol][(c << 5) + (g << 3)];
            accp = __builtin_amdgcn_mfma_f32_16x16x32_bf16(a, b, accp, 0, 0, 0);
        }
        #pragma unroll
        for (int i = 0; i < 4; ++i) va[i] = vb[i];
    }
    #pragma unroll
    for (int r = 0; r < 4; ++r) {
        const int q = (g << 2) + r;
        Cb[(size_t)q * Dn + dcol] = accp[r] * invL[q];
    }

    {
        const int qq = tid >> 4, ii = tid & 15;
        const float inv = invL[qq];
        float* arow = Ab + (size_t)qq * Sn;
        #pragma unroll
        for (int c = 0; c < 16; ++c) {
            const int k0 = (c << 6) + (ii << 2);
            const ushort4 p = *(const ushort4*)&Ph[qq][k0];
            v4f o;
            o[0] = bf2f(p.x) * inv; o[1] = bf2f(p.y) * inv;
            o[2] = bf2f(p.z) * inv; o[3] = bf2f(p.w) * inv;
            *(v4f*)(arow + k0) = o;
        }
    }
}

extern "C" void kernel_launch(void* const* d_in, const int* in_sizes, int n_in,
                              void* d_out, int out_size, void* d_ws, size_t ws_size,
                              hipStream_t stream) {
    const float* Q    = (const float*)d_in[0];
    const float* K    = (const float*)d_in[1];
    const float* V    = (const float*)d_in[2];
    const int*   mask = (const int*)d_in[3];

    float* ctx  = (float*)d_out;                           // (B,H,S,D)
    float* attn = (float*)d_out + (size_t)128 * Sn * Dn;   // (B,H,S,S)

    const size_t NELEM = (size_t)128 * Sn * Dn;            // 8,388,608
    const size_t MWORDS = (size_t)128 * Sn * 16;           // 2,097,152 u64
    const size_t NEED  = NELEM * 2 * 3 + MWORDS * 8;       // 50.3MB + 16.8MB

    if (ws_size >= NEED) {
        unsigned short* Khi = (unsigned short*)d_ws;
        unsigned short* Klo = Khi + NELEM;
        unsigned short* VT  = Klo + NELEM;
        unsigned long long* MWp = (unsigned long long*)((char*)d_ws + NELEM * 2 * 3);
        prep_k<<<4096, 256, 0, stream>>>(K, Khi, Klo);
        prep_v<<<2048, 256, 0, stream>>>(V, VT);
        prep_m<<<2048, 256, 0, stream>>>(mask, MWp);
        fused_attn_r<<<128 * 64, 256, 0, stream>>>(Khi, Klo, VT, Q, MWp, attn, ctx);
    } else {
        fused_attn_fb<<<128 * 64, 256, 0, stream>>>(Q, K, V, mask, attn, ctx);
    }
}

// Round 10
// 293.289 us; speedup vs baseline: 1.7841x; 1.1731x over previous
//
#include <hip/hip_runtime.h>

#define Sn 1024
#define Dn 64
#define PH_LD 1032   // ushorts/row: 516 dw ≡ 4 (mod 32)
#define K_LD 72
#define V_LD 72

typedef short v8s __attribute__((ext_vector_type(8)));
typedef unsigned short v8u __attribute__((ext_vector_type(8)));
typedef float v4f __attribute__((ext_vector_type(4)));
typedef int   v4i __attribute__((ext_vector_type(4)));

#define LGKM0()  asm volatile("s_waitcnt lgkmcnt(0)" ::: "memory")
#define SBAR()   do { asm volatile("" ::: "memory"); __builtin_amdgcn_s_barrier(); \
                      __builtin_amdgcn_sched_barrier(0); } while (0)

__device__ __forceinline__ unsigned short f2bf(float x) {
    union { float f; unsigned u; } v; v.f = x;
    return (unsigned short)((v.u + 0x7FFFu + ((v.u >> 16) & 1u)) >> 16);
}
__device__ __forceinline__ float bf2f(unsigned short h) {
    union { float f; unsigned u; } v; v.u = ((unsigned)h) << 16;
    return v.f;
}
__device__ __forceinline__ void split2(float x, unsigned short& h, unsigned short& l) {
    unsigned short hs = f2bf(x);
    h = hs; l = f2bf(x - bf2f(hs));
}

// ---- prep: K -> fragment-interleaved bf16 hi/lo ----
// KF[bh][kt][w][f][lane][8], f: 0=h0(d=g*8) 1=h1(d=32+g*8) 2=l0 3=l1; lane=g*16+fr
// Fused-kernel fragment load = 64 lanes x 16B contiguous (1KB, fully coalesced).
__global__ __launch_bounds__(256) void prep_kf(const float* __restrict__ K,
    unsigned short* __restrict__ KF)
{
    const int bh = blockIdx.x >> 4, kt = blockIdx.x & 15;
    const int t = threadIdx.x;
    const int w = t >> 6, lane = t & 63;
    const int fr = lane & 15, g = lane >> 4;
    const float* src = K + (((size_t)(bh << 10) + (kt << 6) + (w << 4) + fr) << 6);
    const v4f a0 = __builtin_nontemporal_load((const v4f*)(src + (g << 3)));
    const v4f a1 = __builtin_nontemporal_load((const v4f*)(src + (g << 3) + 4));
    const v4f b0 = __builtin_nontemporal_load((const v4f*)(src + 32 + (g << 3)));
    const v4f b1 = __builtin_nontemporal_load((const v4f*)(src + 32 + (g << 3) + 4));
    v8u h0, h1, l0, l1;
    #pragma unroll
    for (int j = 0; j < 4; ++j) {
        unsigned short hh, ll;
        split2(a0[j], hh, ll); h0[j] = hh;     l0[j] = ll;
        split2(a1[j], hh, ll); h0[4 + j] = hh; l0[4 + j] = ll;
        split2(b0[j], hh, ll); h1[j] = hh;     l1[j] = ll;
        split2(b1[j], hh, ll); h1[4 + j] = hh; l1[4 + j] = ll;
    }
    unsigned short* dst = KF + ((size_t)bh << 17) + ((size_t)((kt << 2) + w) << 11) + (lane << 3);
    *(v8u*)(dst)        = h0;
    *(v8u*)(dst + 512)  = h1;
    *(v8u*)(dst + 1024) = l0;
    *(v8u*)(dst + 1536) = l1;
}

// ---- prep: V -> fragment-interleaved V^T bf16 ----
// VF[bh][kt][w][c][lane][8]: c=0 -> k=kt*64+g*8+j, c=1 -> k=kt*64+32+g*8+j, d=w*16+fr
__global__ __launch_bounds__(256) void prep_vf(const float* __restrict__ V,
    unsigned short* __restrict__ VF)
{
    __shared__ float Ts[64][65];
    const int bh = blockIdx.x >> 4, kt = blockIdx.x & 15;
    const int t = threadIdx.x;
    {
        const int r = t >> 2, cs = (t & 3) << 4;
        const float* src = V + ((size_t)bh * Sn + (kt << 6) + r) * Dn + cs;
        const v4f a = __builtin_nontemporal_load((const v4f*)src);
        const v4f b = __builtin_nontemporal_load((const v4f*)src + 1);
        const v4f c = __builtin_nontemporal_load((const v4f*)src + 2);
        const v4f d = __builtin_nontemporal_load((const v4f*)src + 3);
        #pragma unroll
        for (int j = 0; j < 4; ++j) {
            Ts[r][cs + j]      = a[j];
            Ts[r][cs + 4 + j]  = b[j];
            Ts[r][cs + 8 + j]  = c[j];
            Ts[r][cs + 12 + j] = d[j];
        }
    }
    __syncthreads();
    {
        const int w = t >> 6, lane = t & 63;
        const int fr = lane & 15, g = lane >> 4;
        const int d = (w << 4) + fr;
        unsigned short* dst = VF + ((size_t)bh << 16) + ((size_t)((kt << 2) + w) << 10) + (lane << 3);
        v8u o0, o1;
        #pragma unroll
        for (int j = 0; j < 8; ++j) o0[j] = f2bf(Ts[(g << 3) + j][d]);
        #pragma unroll
        for (int j = 0; j < 8; ++j) o1[j] = f2bf(Ts[32 + (g << 3) + j][d]);
        *(v8u*)dst         = o0;
        *(v8u*)(dst + 512) = o1;
    }
}

// ---- prep: mask int32 -> bit-packed u64 words ----
__global__ __launch_bounds__(256) void prep_m(const int* __restrict__ M,
    unsigned long long* __restrict__ MW)
{
    const int NW = 2097152;
    const int lane = threadIdx.x & 63;
    const int wave = (blockIdx.x << 2) + (threadIdx.x >> 6);
    const int nwaves = gridDim.x << 2;
    for (int w0 = wave << 3; w0 < NW; w0 += nwaves << 3) {
        unsigned long long b[8];
        #pragma unroll
        for (int s = 0; s < 8; ++s) {
            const int v = __builtin_nontemporal_load(&M[((size_t)(w0 + s) << 6) + lane]);
            b[s] = __ballot(v != 0);
        }
        if (lane == 0) {
            ulonglong2* dst = (ulonglong2*)(MW + w0);
            ulonglong2 p0, p1, p2, p3;
            p0.x = b[0]; p0.y = b[1]; p1.x = b[2]; p1.y = b[3];
            p2.x = b[4]; p2.y = b[5]; p3.x = b[6]; p3.y = b[7];
            dst[0] = p0; dst[1] = p1; dst[2] = p2; dst[3] = p3;
        }
    }
}

// ---- fused attention: coalesced fragment loads, NO in-loop barriers ----
// Block: 16 q-rows, 4 waves, 4 blocks/CU (LDS = Ph only, 33 KB).
// Every MFMA fragment = one coalesced 1KB dwordx4 load from L2 (XCD-local).
__global__ __launch_bounds__(256, 4) void fused_attn_c(
    const unsigned short* __restrict__ KFG, const unsigned short* __restrict__ VFG,
    const float* __restrict__ Q, const unsigned long long* __restrict__ MW,
    float* __restrict__ attnO, float* __restrict__ ctxO)
{
    __shared__ unsigned short Ph[16][PH_LD];
    __shared__ float rsumW[4][16];
    __shared__ float invL[16];

    const int tid  = threadIdx.x;
    const int lane = tid & 63;
    const int w    = tid >> 6;
    const int fr   = lane & 15;
    const int g    = lane >> 4;

    // bijective XCD swizzle: all 64 q-blocks of one bh on one XCD
    const int swz = ((blockIdx.x & 7) << 10) + (blockIdx.x >> 3);
    const int bh = swz >> 6;
    const int q0 = (swz & 63) << 4;

    const float* Qb = Q + (size_t)bh * Sn * Dn + (size_t)q0 * Dn;
    float*       Ab = attnO + (size_t)bh * Sn * Sn + (size_t)q0 * Sn;
    float*       Cb = ctxO  + (size_t)bh * Sn * Dn + (size_t)q0 * Dn;
    const unsigned short* KFb = KFG + ((size_t)bh << 17);
    const unsigned short* VFb = VFG + ((size_t)bh << 16);
    const unsigned long long* mwp = MW + ((size_t)bh << 14) + ((size_t)(q0 + fr) << 4);

    // Q B-fragments (once per block)
    v8s qh0, qh1, ql0, ql1;
    {
        const float* qp = Qb + fr * Dn + (g << 3);
        float x0[8], x1[8];
        *(v4f*)&x0[0] = *(const v4f*)qp;
        *(v4f*)&x0[4] = *(const v4f*)(qp + 4);
        *(v4f*)&x1[0] = *(const v4f*)(qp + 32);
        *(v4f*)&x1[4] = *(const v4f*)(qp + 36);
        #pragma unroll
        for (int i = 0; i < 8; ++i) {
            unsigned short hh, ll;
            split2(x0[i], hh, ll); qh0[i] = (short)hh; ql0[i] = (short)ll;
            split2(x1[i], hh, ll); qh1[i] = (short)hh; ql1[i] = (short)ll;
        }
    }

    const int sh = (w << 4) + (g << 2);

#define LDK(kt, h0, h1, l0, l1) do {                                               \
        const unsigned short* _p = KFb + ((size_t)(((kt) << 2) + w) << 11) + (lane << 3); \
        h0 = *(const v8s*)_p;          h1 = *(const v8s*)(_p + 512);               \
        l0 = *(const v8s*)(_p + 1024); l1 = *(const v8s*)(_p + 1536);              \
    } while (0)

#define STEPA(h0, h1, l0, l1, mwv, kt) do {                                        \
        v4f acc = {0.f, 0.f, 0.f, 0.f};                                            \
        __builtin_amdgcn_s_setprio(1);                                             \
        acc = __builtin_amdgcn_mfma_f32_16x16x32_bf16(h0, qh0, acc, 0, 0, 0);      \
        acc = __builtin_amdgcn_mfma_f32_16x16x32_bf16(h1, qh1, acc, 0, 0, 0);      \
        acc = __builtin_amdgcn_mfma_f32_16x16x32_bf16(l0, qh0, acc, 0, 0, 0);      \
        acc = __builtin_amdgcn_mfma_f32_16x16x32_bf16(l1, qh1, acc, 0, 0, 0);      \
        acc = __builtin_amdgcn_mfma_f32_16x16x32_bf16(h0, ql0, acc, 0, 0, 0);      \
        acc = __builtin_amdgcn_mfma_f32_16x16x32_bf16(h1, ql1, acc, 0, 0, 0);      \
        __builtin_amdgcn_s_setprio(0);                                             \
        const unsigned mb = (unsigned)((mwv) >> sh);                               \
        const float e0 = (mb & 1u) ? 1.0f : __expf(acc[0]);                        \
        const float e1 = (mb & 2u) ? 1.0f : __expf(acc[1]);                        \
        const float e2 = (mb & 4u) ? 1.0f : __expf(acc[2]);                        \
        const float e3 = (mb & 8u) ? 1.0f : __expf(acc[3]);                        \
        rs += (e0 + e1) + (e2 + e3);                                               \
        ushort4 pk;                                                                \
        pk.x = f2bf(e0); pk.y = f2bf(e1); pk.z = f2bf(e2); pk.w = f2bf(e3);        \
        *(ushort4*)&Ph[fr][((kt) << 6) + (w << 4) + (g << 2)] = pk;                \
    } while (0)

    float rs = 0.f;

    // ---- Phase A: barrier-free, coalesced frags, 2-deep ping-pong ----
    {
        v8s ah0, ah1, al0, al1, bh0, bh1, bl0, bl1;
        LDK(0, ah0, ah1, al0, al1);
        LDK(1, bh0, bh1, bl0, bl1);
        unsigned long long mA = mwp[0], mB = mwp[1];
        for (int kt = 0; kt < 16; kt += 2) {
            const int k2 = (kt + 2 < 16) ? kt + 2 : kt;
            const int k3 = (kt + 3 < 16) ? kt + 3 : kt;
            v8s ch0, ch1, cl0, cl1, dh0, dh1, dl0, dl1;
            LDK(k2, ch0, ch1, cl0, cl1);
            LDK(k3, dh0, dh1, dl0, dl1);
            const unsigned long long mC = mwp[k2];
            const unsigned long long mD = mwp[k3];
            STEPA(ah0, ah1, al0, al1, mA, kt);
            STEPA(bh0, bh1, bl0, bl1, mB, kt + 1);
            ah0 = ch0; ah1 = ch1; al0 = cl0; al1 = cl1; mA = mC;
            bh0 = dh0; bh1 = dh1; bl0 = dl0; bl1 = dl1; mB = mD;
        }
    }

    // ---- row-sum reduce (the only barriers; raw, no vmcnt drain) ----
    rs += __shfl_xor(rs, 16);
    rs += __shfl_xor(rs, 32);
    if (g == 0) rsumW[w][fr] = rs;
    __builtin_amdgcn_sched_barrier(0);
    LGKM0();
    SBAR();
    if (tid < 16) {
        const float s = rsumW[0][tid] + rsumW[1][tid] + rsumW[2][tid] + rsumW[3][tid];
        invL[tid] = 1.0f / s;
    }
    __builtin_amdgcn_sched_barrier(0);
    LGKM0();
    SBAR();

#define LDV(kt, v0, v1) do {                                                       \
        const unsigned short* _p = VFb + ((size_t)(((kt) << 2) + w) << 10) + (lane << 3); \
        v0 = *(const v8s*)_p;  v1 = *(const v8s*)(_p + 512);                       \
    } while (0)

#define STEPB(v0, v1, kt) do {                                                     \
        const v8s a0 = *(const v8s*)&Ph[fr][((kt) << 6) + (g << 3)];               \
        const v8s a1 = *(const v8s*)&Ph[fr][((kt) << 6) + 32 + (g << 3)];          \
        __builtin_amdgcn_s_setprio(1);                                             \
        accp = __builtin_amdgcn_mfma_f32_16x16x32_bf16(a0, v0, accp, 0, 0, 0);     \
        accp = __builtin_amdgcn_mfma_f32_16x16x32_bf16(a1, v1, accp, 0, 0, 0);     \
        __builtin_amdgcn_s_setprio(0);                                             \
    } while (0)

    // Issue first V frag loads BEFORE the attn store burst: vmcnt retires in
    // order, so loads-before-stores means Phase B never waits on the stores.
    v8s va0, va1, vb0, vb1;
    LDV(0, va0, va1);
    LDV(1, vb0, vb1);

    // ---- write normalized attn (NT burst drains under Phase B) ----
    {
        const int qq = tid >> 4, ii = tid & 15;
        const float inv = invL[qq];
        float* arow = Ab + (size_t)qq * Sn;
        #pragma unroll
        for (int c = 0; c < 16; ++c) {
            const int k0 = (c << 6) + (ii << 2);
            const ushort4 p = *(const ushort4*)&Ph[qq][k0];
            v4f o;
            o[0] = bf2f(p.x) * inv; o[1] = bf2f(p.y) * inv;
            o[2] = bf2f(p.z) * inv; o[3] = bf2f(p.w) * inv;
            __builtin_nontemporal_store(o, (v4f*)(arow + k0));
        }
    }

    // ---- Phase B: barrier-free, coalesced V frags ----
    const int dcol = (w << 4) + fr;
    v4f accp = {0.f, 0.f, 0.f, 0.f};
    for (int kt = 0; kt < 16; kt += 2) {
        const int k2 = (kt + 2 < 16) ? kt + 2 : kt;
        const int k3 = (kt + 3 < 16) ? kt + 3 : kt;
        v8s vc0, vc1, vd0, vd1;
        LDV(k2, vc0, vc1);
        LDV(k3, vd0, vd1);
        STEPB(va0, va1, kt);
        STEPB(vb0, vb1, kt + 1);
        va0 = vc0; va1 = vc1;
        vb0 = vd0; vb1 = vd1;
    }
    #pragma unroll
    for (int r = 0; r < 4; ++r) {
        const int q = (g << 2) + r;
        __builtin_nontemporal_store(accp[r] * invL[q], &Cb[(size_t)q * Dn + dcol]);
    }
#undef LDK
#undef STEPA
#undef LDV
#undef STEPB
}

// ---------------- fallback (round-3 kernel, in-kernel split) ----------------
__global__ __launch_bounds__(256, 3) void fused_attn_fb(
    const float* __restrict__ Q, const float* __restrict__ K,
    const float* __restrict__ V, const int* __restrict__ M,
    float* __restrict__ attnO, float* __restrict__ ctxO)
{
    __shared__ unsigned short Ph[16][1048];
    __shared__ __align__(16) unsigned short Kraw[2 * 64 * K_LD];
    __shared__ float rsumW[4][16];
    __shared__ float invL[16];

    unsigned short (*Khi)[K_LD] = (unsigned short (*)[K_LD])Kraw;
    unsigned short (*Klo)[K_LD] = (unsigned short (*)[K_LD])(Kraw + 64 * K_LD);
    unsigned short (*Vt)[V_LD]  = (unsigned short (*)[V_LD])Kraw;

    const int tid  = threadIdx.x;
    const int lane = tid & 63;
    const int w    = tid >> 6;
    const int fr   = lane & 15;
    const int g    = lane >> 4;

    const int bh = blockIdx.x >> 6;
    const int q0 = (blockIdx.x & 63) << 4;

    const float* Qb = Q + (size_t)bh * Sn * Dn + (size_t)q0 * Dn;
    const float* Kb = K + (size_t)bh * Sn * Dn;
    const float* Vb = V + (size_t)bh * Sn * Dn;
    const int*   Mb = M + (size_t)bh * Sn * Sn + (size_t)q0 * Sn;
    float*       Ab = attnO + (size_t)bh * Sn * Sn + (size_t)q0 * Sn;
    float*       Cb = ctxO  + (size_t)bh * Sn * Dn + (size_t)q0 * Dn;

    v8s qh0, qh1, ql0, ql1;
    {
        const float* qp = Qb + fr * Dn + (g << 3);
        float x0[8], x1[8];
        *(v4f*)&x0[0] = *(const v4f*)qp;
        *(v4f*)&x0[4] = *(const v4f*)(qp + 4);
        *(v4f*)&x1[0] = *(const v4f*)(qp + 32);
        *(v4f*)&x1[4] = *(const v4f*)(qp + 36);
        #pragma unroll
        for (int i = 0; i < 8; ++i) {
            unsigned short hh, ll;
            split2(x0[i], hh, ll); qh0[i] = (short)hh; ql0[i] = (short)ll;
            split2(x1[i], hh, ll); qh1[i] = (short)hh; ql1[i] = (short)ll;
        }
    }

    const int srow = tid >> 4;
    const int sc4  = (tid & 15) << 2;

    const int* mp = Mb + (size_t)fr * Sn + (w << 4) + (g << 2);
    v4i mv = *(const v4i*)mp;

    v4f ka[4];
    #pragma unroll
    for (int i = 0; i < 4; ++i)
        ka[i] = *(const v4f*)(Kb + (size_t)(srow + (i << 4)) * Dn + sc4);

    float rs = 0.f;

    for (int kt = 0; kt < 16; ++kt) {
        __syncthreads();
        v4f kb[4];
        if (kt < 15) {
            const float* kn = Kb + (size_t)((kt + 1) << 6) * Dn;
            #pragma unroll
            for (int i = 0; i < 4; ++i)
                kb[i] = *(const v4f*)(kn + (size_t)(srow + (i << 4)) * Dn + sc4);
        }
        v4i mnext = mv;
        if (kt < 15) mnext = *(const v4i*)(mp + ((kt + 1) << 6));

        #pragma unroll
        for (int i = 0; i < 4; ++i) {
            const int row = srow + (i << 4);
            ushort4 hv, lv;
            split2(ka[i][0], hv.x, lv.x); split2(ka[i][1], hv.y, lv.y);
            split2(ka[i][2], hv.z, lv.z); split2(ka[i][3], hv.w, lv.w);
            *(ushort4*)&Khi[row][sc4] = hv;
            *(ushort4*)&Klo[row][sc4] = lv;
        }
        __syncthreads();

        const int krow = (w << 4) + fr;
        const v8s kh0 = *(const v8s*)&Khi[krow][(g << 3)];
        const v8s kh1 = *(const v8s*)&Khi[krow][32 + (g << 3)];
        const v8s kl0 = *(const v8s*)&Klo[krow][(g << 3)];
        const v8s kl1 = *(const v8s*)&Klo[krow][32 + (g << 3)];

        v4f acc = {0.f, 0.f, 0.f, 0.f};
        acc = __builtin_amdgcn_mfma_f32_16x16x32_bf16(kh0, qh0, acc, 0, 0, 0);
        acc = __builtin_amdgcn_mfma_f32_16x16x32_bf16(kh1, qh1, acc, 0, 0, 0);
        acc = __builtin_amdgcn_mfma_f32_16x16x32_bf16(kl0, qh0, acc, 0, 0, 0);
        acc = __builtin_amdgcn_mfma_f32_16x16x32_bf16(kl1, qh1, acc, 0, 0, 0);
        acc = __builtin_amdgcn_mfma_f32_16x16x32_bf16(kh0, ql0, acc, 0, 0, 0);
        acc = __builtin_amdgcn_mfma_f32_16x16x32_bf16(kh1, ql1, acc, 0, 0, 0);

        const float e0 = mv[0] ? 1.0f : __expf(acc[0]);
        const float e1 = mv[1] ? 1.0f : __expf(acc[1]);
        const float e2 = mv[2] ? 1.0f : __expf(acc[2]);
        const float e3 = mv[3] ? 1.0f : __expf(acc[3]);
        rs += (e0 + e1) + (e2 + e3);
        ushort4 pk;
        pk.x = f2bf(e0); pk.y = f2bf(e1); pk.z = f2bf(e2); pk.w = f2bf(e3);
        *(ushort4*)&Ph[fr][(kt << 6) + (w << 4) + (g << 2)] = pk;

        mv = mnext;
        #pragma unroll
        for (int i = 0; i < 4; ++i) ka[i] = kb[i];
    }

    rs += __shfl_xor(rs, 16);
    rs += __shfl_xor(rs, 32);
    if (g == 0) rsumW[w][fr] = rs;
    __syncthreads();
    if (tid < 16) {
        const float s = rsumW[0][tid] + rsumW[1][tid] + rsumW[2][tid] + rsumW[3][tid];
        invL[tid] = 1.0f / s;
    }
    __syncthreads();

    const int dcol = (w << 4) + fr;
    v4f va[4];
    #pragma unroll
    for (int i = 0; i < 4; ++i)
        va[i] = *(const v4f*)(Vb + (size_t)(srow + (i << 4)) * Dn + sc4);

    v4f accp = {0.f, 0.f, 0.f, 0.f};
    for (int kt = 0; kt < 16; ++kt) {
        __syncthreads();
        v4f vb[4];
        if (kt < 15) {
            const float* vn = Vb + (size_t)((kt + 1) << 6) * Dn;
            #pragma unroll
            for (int i = 0; i < 4; ++i)
                vb[i] = *(const v4f*)(vn + (size_t)(srow + (i << 4)) * Dn + sc4);
        }
        #pragma unroll
        for (int i = 0; i < 4; ++i) {
            const int row = srow + (i << 4);
            Vt[sc4 + 0][row] = f2bf(va[i][0]);
            Vt[sc4 + 1][row] = f2bf(va[i][1]);
            Vt[sc4 + 2][row] = f2bf(va[i][2]);
            Vt[sc4 + 3][row] = f2bf(va[i][3]);
        }
        __syncthreads();

        #pragma unroll
        for (int c = 0; c < 2; ++c) {
            const int kc = (kt << 6) + (c << 5);
            const v8s a = *(const v8s*)&Ph[fr][kc + (g << 3)];
            const v8s b = *(const v8s*)&Vt[dcol][(c << 5) + (g << 3)];
            accp = __builtin_amdgcn_mfma_f32_16x16x32_bf16(a, b, accp, 0, 0, 0);
        }
        #pragma unroll
        for (int i = 0; i < 4; ++i) va[i] = vb[i];
    }
    #pragma unroll
    for (int r = 0; r < 4; ++r) {
        const int q = (g << 2) + r;
        Cb[(size_t)q * Dn + dcol] = accp[r] * invL[q];
    }

    {
        const int qq = tid >> 4, ii = tid & 15;
        const float inv = invL[qq];
        float* arow = Ab + (size_t)qq * Sn;
        #pragma unroll
        for (int c = 0; c < 16; ++c) {
            const int k0 = (c << 6) + (ii << 2);
            const ushort4 p = *(const ushort4*)&Ph[qq][k0];
            v4f o;
            o[0] = bf2f(p.x) * inv; o[1] = bf2f(p.y) * inv;
            o[2] = bf2f(p.z) * inv; o[3] = bf2f(p.w) * inv;
            *(v4f*)(arow + k0) = o;
        }
    }
}

extern "C" void kernel_launch(void* const* d_in, const int* in_sizes, int n_in,
                              void* d_out, int out_size, void* d_ws, size_t ws_size,
                              hipStream_t stream) {
    const float* Q    = (const float*)d_in[0];
    const float* K    = (const float*)d_in[1];
    const float* V    = (const float*)d_in[2];
    const int*   mask = (const int*)d_in[3];

    float* ctx  = (float*)d_out;                           // (B,H,S,D)
    float* attn = (float*)d_out + (size_t)128 * Sn * Dn;   // (B,H,S,S)

    const size_t NELEM = (size_t)128 * Sn * Dn;            // 8,388,608
    const size_t MWORDS = (size_t)128 * Sn * 16;           // 2,097,152 u64
    const size_t NEED  = NELEM * 2 * 3 + MWORDS * 8;       // 50.3MB + 16.8MB

    if (ws_size >= NEED) {
        unsigned short* KF = (unsigned short*)d_ws;        // 33.5 MB (hi/lo frag-interleaved)
        unsigned short* VF = KF + NELEM * 2;               // 16.8 MB (V^T frag-interleaved)
        unsigned long long* MWp = (unsigned long long*)((char*)d_ws + NELEM * 2 * 3);
        prep_kf<<<2048, 256, 0, stream>>>(K, KF);
        prep_vf<<<2048, 256, 0, stream>>>(V, VF);
        prep_m<<<2048, 256, 0, stream>>>(mask, MWp);
        fused_attn_c<<<128 * 64, 256, 0, stream>>>(KF, VF, Q, MWp, attn, ctx);
    } else {
        fused_attn_fb<<<128 * 64, 256, 0, stream>>>(Q, K, V, mask, attn, ctx);
    }
}